// Round 2
// baseline (1133.239 us; speedup 1.0000x reference)
//
#include <hip/hip_runtime.h>
#include <hip/hip_fp16.h>
#include <math.h>

#define Cc 256
#define NH 8
#define HD 32
#define Tt 256
#define MH 256
#define TBL 961  // 31*31 distinct relative offsets

// ---------------------------------------------------------------------------
// Kernel 1: bias MLP evaluated on the 961 distinct (di,dj) pairs only.
// table[h][961], tablemax[h] = max over table (safe softmax shift bound).
// ---------------------------------------------------------------------------
__global__ __launch_bounds__(256) void table_kernel(
    const float* __restrict__ mw1, const float* __restrict__ mb1,
    const float* __restrict__ mw2, const float* __restrict__ mb2,
    float* __restrict__ table, float* __restrict__ tablemax) {
  __shared__ float s_w1a[MH], s_w1b[MH], s_b1[MH];
  __shared__ float s_w2[NH * MH];
  __shared__ float red[256];
  int tid = threadIdx.x;
  for (int i = tid; i < MH; i += 256) {
    s_w1a[i] = mw1[2 * i];
    s_w1b[i] = mw1[2 * i + 1];
    s_b1[i] = mb1[i];
  }
  for (int i = tid; i < NH * MH; i += 256) s_w2[i] = mw2[i];
  __syncthreads();

  float lmax[NH];
#pragma unroll
  for (int j = 0; j < NH; j++) lmax[j] = -1e30f;

  for (int idx = tid; idx < TBL; idx += 256) {
    float fdi = (float)(idx / 31 - 15);
    float fdj = (float)(idx % 31 - 15);
    float d0 = (fdi > 0.f ? 1.f : (fdi < 0.f ? -1.f : 0.f)) * log1pf(fabsf(fdi));
    float d1 = (fdj > 0.f ? 1.f : (fdj < 0.f ? -1.f : 0.f)) * log1pf(fabsf(fdj));
    float o[NH];
#pragma unroll
    for (int j = 0; j < NH; j++) o[j] = mb2[j];
    for (int m = 0; m < MH; m++) {
      float hid = fmaxf(fmaf(d0, s_w1a[m], fmaf(d1, s_w1b[m], s_b1[m])), 0.f);
#pragma unroll
      for (int j = 0; j < NH; j++) o[j] = fmaf(hid, s_w2[j * MH + m], o[j]);
    }
#pragma unroll
    for (int j = 0; j < NH; j++) {
      table[j * TBL + idx] = o[j];
      lmax[j] = fmaxf(lmax[j], o[j]);
    }
  }

  for (int j = 0; j < NH; j++) {
    __syncthreads();
    red[tid] = lmax[j];
    __syncthreads();
    for (int s = 128; s > 0; s >>= 1) {
      if (tid < s) red[tid] = fmaxf(red[tid], red[tid + s]);
      __syncthreads();
    }
    if (tid == 0) tablemax[j] = red[0];
  }
}

// ---------------------------------------------------------------------------
// Kernel 2: fused QKV-GEMM + cosine-sim attention.  One block per (b,h).
// Phase 1: qkv[T=256][96] = x[b]^T @ Wh^T + bias, accumulated in registers,
//          written to LDS Qs/Ks/Vs.
// Phase 2: per-thread q-row attention with LDS bias-table lookup, bounded-exp
//          softmax (shift by tablemax[h] + rtau; |cos|<=1 Cauchy-Schwarz).
// Output attnH fp16 in [B][nh][T][hd].
// ---------------------------------------------------------------------------
__global__ __launch_bounds__(256, 1) void fused_attn(
    const float* __restrict__ x, const float* __restrict__ w_qkv,
    const float* __restrict__ b_qkv, const float* __restrict__ table,
    const float* __restrict__ tablemax, const float* __restrict__ tau,
    __half* __restrict__ attnH) {
  __shared__ __align__(16) float Qs[Tt * HD];   // 32 KB
  __shared__ __align__(16) float Ks[Tt * HD];   // 32 KB
  __shared__ __align__(16) float Vs[Tt * HD];   // 32 KB
  __shared__ __align__(16) float Xs[16 * 256];  // 16 KB
  __shared__ __align__(16) float Wss[16 * 96];  // 6 KB
  __shared__ float tb[TBL];                     // 3.8 KB
  __shared__ float kn[Tt];                      // 1 KB
  int tid = threadIdx.x;
  int bh = blockIdx.x, b = bh >> 3, h = bh & 7;

  for (int i = tid; i < TBL; i += 256) tb[i] = table[h * TBL + i];

  // ---- Phase 1: QKV GEMM.  thread (tm,tn): m = tm*16+i (16), n = tn*6+j (6)
  int tn = tid & 15, tm = tid >> 4;
  float bj[6];
#pragma unroll
  for (int j = 0; j < 6; j++) {
    int n = tn * 6 + j;
    int row = ((n >> 5) << 8) + (h << 5) + (n & 31);
    bj[j] = b_qkv[row];
  }

  float acc[16][6] = {};
  const float4* xg = (const float4*)(x + (size_t)b * (Cc * Tt));
  int wkc = tid & 15, wj0 = tid >> 4;

  for (int c0 = 0; c0 < Cc; c0 += 16) {
    // stage x chunk [16 c][256 t] (flat-coalesced float4)
#pragma unroll
    for (int it = 0; it < 4; it++)
      ((float4*)Xs)[it * 256 + tid] = xg[c0 * 64 + it * 256 + tid];
    // stage W chunk transposed -> Wss[kc][j]
#pragma unroll
    for (int r = 0; r < 6; r++) {
      int j = wj0 + 16 * r;
      int row = ((j >> 5) << 8) + (h << 5) + (j & 31);
      Wss[wkc * 96 + j] = w_qkv[(size_t)row * Cc + c0 + wkc];
    }
    __syncthreads();
#pragma unroll
    for (int kk = 0; kk < 16; kk++) {
      const float4* xr = (const float4*)(Xs + kk * 256 + tm * 16);
      float4 a0 = xr[0], a1 = xr[1], a2 = xr[2], a3 = xr[3];
      const float2* wr = (const float2*)(Wss + kk * 96 + tn * 6);
      float2 w0 = wr[0], w1 = wr[1], w2 = wr[2];
      float a[16] = {a0.x, a0.y, a0.z, a0.w, a1.x, a1.y, a1.z, a1.w,
                     a2.x, a2.y, a2.z, a2.w, a3.x, a3.y, a3.z, a3.w};
      float bb[6] = {w0.x, w0.y, w1.x, w1.y, w2.x, w2.y};
#pragma unroll
      for (int i = 0; i < 16; i++)
#pragma unroll
        for (int j = 0; j < 6; j++) acc[i][j] = fmaf(a[i], bb[j], acc[i][j]);
    }
    __syncthreads();
  }

  // write q/k/v tiles to LDS
#pragma unroll
  for (int i = 0; i < 16; i++) {
    int m = tm * 16 + i;
#pragma unroll
    for (int j = 0; j < 6; j++) {
      int n = tn * 6 + j;
      float v = acc[i][j] + bj[j];
      float* dst = (n < 32) ? Qs : ((n < 64) ? Ks : Vs);
      dst[m * HD + (n & 31)] = v;
    }
  }
  __syncthreads();

  // ---- Phase 2: attention.  thread = q row (q = tid)
  {
    const float4* kr = (const float4*)(Ks + tid * HD);
    float s = 0.f;
#pragma unroll
    for (int j = 0; j < 8; j++) {
      float4 kv = kr[j];
      s = fmaf(kv.x, kv.x, s); s = fmaf(kv.y, kv.y, s);
      s = fmaf(kv.z, kv.z, s); s = fmaf(kv.w, kv.w, s);
    }
    kn[tid] = sqrtf(s);
  }
  float q[HD];
  float qn = 0.f;
  {
    const float4* qr = (const float4*)(Qs + tid * HD);
#pragma unroll
    for (int j = 0; j < 8; j++) {
      float4 qv = qr[j];
      q[4 * j + 0] = qv.x; q[4 * j + 1] = qv.y;
      q[4 * j + 2] = qv.z; q[4 * j + 3] = qv.w;
      qn = fmaf(qv.x, qv.x, qn); qn = fmaf(qv.y, qv.y, qn);
      qn = fmaf(qv.z, qv.z, qn); qn = fmaf(qv.w, qv.w, qn);
    }
    qn = sqrtf(qn);
  }
  float rtau = 1.0f / fmaxf(tau[h], 0.01f);
  float shift = tablemax[h] + rtau * 1.0001f;  // >= max_k score (safe bound)
  int qi = tid >> 4, qj = tid & 15;
  __syncthreads();  // kn[] visible

  float accv[HD];
#pragma unroll
  for (int j = 0; j < HD; j++) accv[j] = 0.f;
  float l = 0.f;

#pragma unroll 2
  for (int k = 0; k < Tt; k++) {
    const float4* kr = (const float4*)(Ks + k * HD);
    float da = 0.f, db = 0.f, dc = 0.f, dd = 0.f;
#pragma unroll
    for (int j = 0; j < 8; j++) {
      float4 kv = kr[j];
      da = fmaf(q[4 * j + 0], kv.x, da);
      db = fmaf(q[4 * j + 1], kv.y, db);
      dc = fmaf(q[4 * j + 2], kv.z, dc);
      dd = fmaf(q[4 * j + 3], kv.w, dd);
    }
    float dot = (da + db) + (dc + dd);
    float bias = tb[(qi - (k >> 4) + 15) * 31 + (qj - (k & 15) + 15)];
    float d = fmaxf(qn * kn[k], 1e-6f);
    float sc = fmaf(dot * __builtin_amdgcn_rcpf(d), rtau, bias - shift);
    float p = __expf(sc);
    l += p;
    const float4* vr = (const float4*)(Vs + k * HD);
#pragma unroll
    for (int j = 0; j < 8; j++) {
      float4 vv = vr[j];
      accv[4 * j + 0] = fmaf(p, vv.x, accv[4 * j + 0]);
      accv[4 * j + 1] = fmaf(p, vv.y, accv[4 * j + 1]);
      accv[4 * j + 2] = fmaf(p, vv.z, accv[4 * j + 2]);
      accv[4 * j + 3] = fmaf(p, vv.w, accv[4 * j + 3]);
    }
  }

  float rl = 1.0f / l;
  union { __half2 h2; unsigned int u; } cv;
  unsigned int pu[16];
#pragma unroll
  for (int e = 0; e < 16; e++) {
    cv.h2 = __floats2half2_rn(accv[2 * e] * rl, accv[2 * e + 1] * rl);
    pu[e] = cv.u;
  }
  uint4* dst = (uint4*)(attnH + ((size_t)bh * Tt + tid) * HD);
#pragma unroll
  for (int w = 0; w < 4; w++) {
    uint4 u;
    u.x = pu[4 * w + 0]; u.y = pu[4 * w + 1];
    u.z = pu[4 * w + 2]; u.w = pu[4 * w + 3];
    dst[w] = u;
  }
}

// ---------------------------------------------------------------------------
// Kernel 3: proj GEMM (A fp16) + output transpose to [B][C][T].
// out[b][c][t] = sum_k attnH[b][k>>5][t][k&31] * w_proj[c][k] + b_proj[c]
// ---------------------------------------------------------------------------
__global__ __launch_bounds__(256) void proj_gemm(
    const __half* __restrict__ A, const float* __restrict__ w,
    const float* __restrict__ bp, float* __restrict__ out) {
  __shared__ __align__(16) float As[16][68];
  __shared__ __align__(16) float Bs[16][68];
  __shared__ __align__(16) float Cs[64][65];
  int tid = threadIdx.x;
  int row0 = blockIdx.x * 64;
  int n0 = blockIdx.y * 64;
  int b = row0 >> 8, t0 = row0 & 255;
  int col_t = tid & 15, row_t = tid >> 4;
  int akc = tid & 15, am0 = tid >> 4;

  float acc[4][4] = {};
  for (int k0 = 0; k0 < Cc; k0 += 16) {
    {
      int kc = k0 + akc;
      int head = kc >> 5, jj = kc & 31;
      const __half* ap = A + ((size_t)(b * NH + head) * Tt + t0) * HD + jj;
#pragma unroll
      for (int p = 0; p < 4; p++) {
        int m = am0 + p * 16;
        As[akc][m] = __half2float(ap[(size_t)m * HD]);
      }
    }
#pragma unroll
    for (int p = 0; p < 4; p++)
      Bs[akc][am0 + p * 16] = w[(size_t)(n0 + am0 + p * 16) * Cc + k0 + akc];
    __syncthreads();
#pragma unroll
    for (int kk = 0; kk < 16; kk++) {
      const float4 a4 = *(const float4*)&As[kk][row_t * 4];
      const float4 b4 = *(const float4*)&Bs[kk][col_t * 4];
      const float av[4] = {a4.x, a4.y, a4.z, a4.w};
      const float bv[4] = {b4.x, b4.y, b4.z, b4.w};
#pragma unroll
      for (int i = 0; i < 4; i++)
#pragma unroll
        for (int j = 0; j < 4; j++) acc[i][j] = fmaf(av[i], bv[j], acc[i][j]);
    }
    __syncthreads();
  }

#pragma unroll
  for (int j = 0; j < 4; j++)
#pragma unroll
    for (int i = 0; i < 4; i++)
      Cs[col_t * 4 + j][row_t * 4 + i] = acc[i][j];
  __syncthreads();

  int t63 = tid & 63, ng = tid >> 6;
#pragma unroll
  for (int p = 0; p < 16; p++) {
    int nl = ng + p * 4;
    int n = n0 + nl;
    out[(size_t)b * (Cc * Tt) + (size_t)n * Tt + t0 + t63] =
        Cs[nl][t63] + bp[n];
  }
}

// ---------------------------------------------------------------------------
extern "C" void kernel_launch(void* const* d_in, const int* in_sizes, int n_in,
                              void* d_out, int out_size, void* d_ws,
                              size_t ws_size, hipStream_t stream) {
  const float* x = (const float*)d_in[0];
  const float* w_qkv = (const float*)d_in[1];
  const float* b_qkv = (const float*)d_in[2];
  const float* w_proj = (const float*)d_in[3];
  const float* b_proj = (const float*)d_in[4];
  const float* mw1 = (const float*)d_in[5];
  const float* mb1 = (const float*)d_in[6];
  const float* mw2 = (const float*)d_in[7];
  const float* mb2 = (const float*)d_in[8];
  const float* tau = (const float*)d_in[9];
  float* out = (float*)d_out;

  // workspace: table 7688 f | tablemax 8 f | attnH 16.7M halves  => 33.59 MB
  const size_t NEEDED = (size_t)(TBL * NH + NH) * 4 +
                        (size_t)256 * NH * Tt * HD * 2;
  if (ws_size < NEEDED) return;  // diagnostic: fail validation, don't fault

  float* table = (float*)d_ws;
  float* tablemax = table + TBL * NH;
  __half* attnH = (__half*)(tablemax + NH);

  table_kernel<<<1, 256, 0, stream>>>(mw1, mb1, mw2, mb2, table, tablemax);
  fused_attn<<<256 * NH, 256, 0, stream>>>(x, w_qkv, b_qkv, table, tablemax,
                                           tau, attnH);
  dim3 g3(1024, 4);
  proj_gemm<<<g3, 256, 0, stream>>>(attnH, w_proj, b_proj, out);
}

// Round 3
// 460.807 us; speedup vs baseline: 2.4592x; 2.4592x over previous
//
#include <hip/hip_runtime.h>
#include <math.h>

#define Cc 256
#define NH 8
#define HD 32
#define Tt 256
#define MH 256
#define TBL 961  // 31*31 distinct relative offsets

typedef _Float16 f16;
typedef f16 f16x8 __attribute__((ext_vector_type(8)));
typedef float f32x4 __attribute__((ext_vector_type(4)));

// XOR-swizzled fp16 index: 16B chunks of a row rotated by (row>>2)&3.
// Cancels quad-stride bank collisions for both MFMA fragment reads and
// C-layout scatter writes (reg stride = 4 rows = key period).
__device__ __forceinline__ int xidx(int row, int col, int stride) {
  return row * stride + (((col >> 3) ^ ((row >> 2) & 3)) << 3) + (col & 7);
}
// Vt variant: row = d (stride 272), col = t (32 chunks), key (d>>2)&3
__device__ __forceinline__ int vidx(int d, int t) {
  return d * 272 + (((t >> 3) ^ ((d >> 2) & 3)) << 3) + (t & 7);
}

// ---------------------------------------------------------------------------
// Kernel 1: bias MLP on the 961 distinct (di,dj) pairs. Unchanged from R2.
// ---------------------------------------------------------------------------
__global__ __launch_bounds__(256) void table_kernel(
    const float* __restrict__ mw1, const float* __restrict__ mb1,
    const float* __restrict__ mw2, const float* __restrict__ mb2,
    float* __restrict__ table, float* __restrict__ tablemax) {
  __shared__ float s_w1a[MH], s_w1b[MH], s_b1[MH];
  __shared__ float s_w2[NH * MH];
  __shared__ float red[256];
  int tid = threadIdx.x;
  for (int i = tid; i < MH; i += 256) {
    s_w1a[i] = mw1[2 * i];
    s_w1b[i] = mw1[2 * i + 1];
    s_b1[i] = mb1[i];
  }
  for (int i = tid; i < NH * MH; i += 256) s_w2[i] = mw2[i];
  __syncthreads();

  float lmax[NH];
#pragma unroll
  for (int j = 0; j < NH; j++) lmax[j] = -1e30f;

  for (int idx = tid; idx < TBL; idx += 256) {
    float fdi = (float)(idx / 31 - 15);
    float fdj = (float)(idx % 31 - 15);
    float d0 = (fdi > 0.f ? 1.f : (fdi < 0.f ? -1.f : 0.f)) * log1pf(fabsf(fdi));
    float d1 = (fdj > 0.f ? 1.f : (fdj < 0.f ? -1.f : 0.f)) * log1pf(fabsf(fdj));
    float o[NH];
#pragma unroll
    for (int j = 0; j < NH; j++) o[j] = mb2[j];
    for (int m = 0; m < MH; m++) {
      float hid = fmaxf(fmaf(d0, s_w1a[m], fmaf(d1, s_w1b[m], s_b1[m])), 0.f);
#pragma unroll
      for (int j = 0; j < NH; j++) o[j] = fmaf(hid, s_w2[j * MH + m], o[j]);
    }
#pragma unroll
    for (int j = 0; j < NH; j++) {
      table[j * TBL + idx] = o[j];
      lmax[j] = fmaxf(lmax[j], o[j]);
    }
  }

  for (int j = 0; j < NH; j++) {
    __syncthreads();
    red[tid] = lmax[j];
    __syncthreads();
    for (int s = 128; s > 0; s >>= 1) {
      if (tid < s) red[tid] = fmaxf(red[tid], red[tid + s]);
      __syncthreads();
    }
    if (tid == 0) tablemax[j] = red[0];
  }
}

// ---------------------------------------------------------------------------
// Kernel 2: fully-MFMA fused QKV + cosine-sim attention. Block = (b,h),
// 512 threads = 8 waves, each wave owns 32 q-rows. No barriers in phase 2.
// Output attnH fp16 in [B][T][C] (proj-friendly row-major).
// ---------------------------------------------------------------------------
__global__ __launch_bounds__(512, 1) void fused_attn(
    const float* __restrict__ x, const float* __restrict__ w_qkv,
    const float* __restrict__ b_qkv, const float* __restrict__ table,
    const float* __restrict__ tablemax, const float* __restrict__ tau,
    f16* __restrict__ attnH) {
  __shared__ f16 Qa[256 * 40];    // [t][32d], stride 40, XOR-swizzled
  __shared__ f16 Ka[256 * 40];
  __shared__ f16 Vt[32 * 272];    // [d][256t], stride 272, XOR-swizzled
  __shared__ f16 Pw[8 * 32 * 72]; // per-wave private P: [32 rows][64+8]
  __shared__ float tb2[31 * 32];  // log2-domain pre-shifted bias
  __shared__ float rqn[256], rkn[256];

  f16* Xa = Pw;          // phase-1 staging aliases Pw: 256*40 fp16
  f16* Wa = Pw + 10240;  // 96*40 fp16

  int tid = threadIdx.x;
  int bh = blockIdx.x, b = bh >> 3, h = bh & 7;
  int wv = tid >> 6, ln = tid & 63, lq = ln >> 4, lm = ln & 15;

  const float LOG2E = 1.4426950408889634f;
  float rtau = 1.0f / fmaxf(tau[h], 0.01f);
  float tmaxh = tablemax[h];
  for (int i = tid; i < TBL; i += 512) {
    int di_ = i / 31, dj_ = i % 31;
    tb2[di_ * 32 + dj_] = (table[h * TBL + i] - tmaxh - rtau * 1.0001f) * LOG2E;
  }

  // per-lane qkv bias for the 6 n-tiles (n = nt*16 + lm)
  float bj[6];
#pragma unroll
  for (int nt = 0; nt < 6; nt++) {
    int n = nt * 16 + lm;
    int row = ((n >> 5) << 8) + (h << 5) + (n & 31);
    bj[nt] = b_qkv[row];
  }

  // ---- Phase 1: QKV GEMM, M=256 N=96 K=256, MFMA 16x16x32_f16
  f32x4 acc[2][6] = {};
  for (int c0 = 0; c0 < Cc; c0 += 32) {
    {  // stage Xa[t][c'] fp16 (transpose of x[b][c][t]); coalesced reads
      int t = tid & 255, cg = tid >> 8;  // cg: which 16 of 32 channels
      f16 tmp[16];
#pragma unroll
      for (int cc = 0; cc < 16; cc++)
        tmp[cc] = (f16)x[(size_t)b * 65536 + (size_t)(c0 + cg * 16 + cc) * 256 + t];
#pragma unroll
      for (int u = 0; u < 2; u++) {
        int pc = (cg * 2 + u) ^ ((t >> 2) & 3);
        *(f16x8*)&Xa[t * 40 + pc * 8] = *(f16x8*)&tmp[u * 8];
      }
    }
    if (tid < 384) {  // stage Wa[n][c'] fp16
      int n = tid >> 2, ck = tid & 3;
      int row = ((n >> 5) << 8) + (h << 5) + (n & 31);
      const float* wp = w_qkv + (size_t)row * Cc + c0 + ck * 8;
      f16 tmp[8];
#pragma unroll
      for (int u = 0; u < 8; u++) tmp[u] = (f16)wp[u];
      int pc = ck ^ ((n >> 2) & 3);
      *(f16x8*)&Wa[n * 40 + pc * 8] = *(f16x8*)tmp;
    }
    __syncthreads();
    f16x8 af[2], bf[6];
#pragma unroll
    for (int e = 0; e < 2; e++)
      af[e] = *(f16x8*)&Xa[xidx(wv * 32 + e * 16 + lm, lq * 8, 40)];
#pragma unroll
    for (int nt = 0; nt < 6; nt++)
      bf[nt] = *(f16x8*)&Wa[xidx(nt * 16 + lm, lq * 8, 40)];
#pragma unroll
    for (int e = 0; e < 2; e++)
#pragma unroll
      for (int nt = 0; nt < 6; nt++)
        acc[e][nt] = __builtin_amdgcn_mfma_f32_16x16x32_f16(af[e], bf[nt],
                                                            acc[e][nt], 0, 0, 0);
    __syncthreads();
  }

  // epilogue: + bias, scatter to Qa/Ka (t-major) and Vt (d-major, transposed)
#pragma unroll
  for (int e = 0; e < 2; e++) {
#pragma unroll
    for (int nt = 0; nt < 6; nt++) {
      int d = (nt & 1) * 16 + lm;
#pragma unroll
      for (int r = 0; r < 4; r++) {
        int t = wv * 32 + e * 16 + lq * 4 + r;
        f16 v = (f16)(acc[e][nt][r] + bj[nt]);
        if (nt < 2)      Qa[xidx(t, d, 40)] = v;
        else if (nt < 4) Ka[xidx(t, d, 40)] = v;
        else             Vt[vidx(d, t)] = v;
      }
    }
  }
  __syncthreads();

  // norms (XOR-permuted chunk order is irrelevant for a sum)
  if (tid < 256) {
    float s = 0.f;
#pragma unroll
    for (int ck = 0; ck < 4; ck++) {
      f16x8 v = *(f16x8*)&Qa[tid * 40 + ck * 8];
#pragma unroll
      for (int u = 0; u < 8; u++) { float f = (float)v[u]; s = fmaf(f, f, s); }
    }
    rqn[tid] = rsqrtf(s) * (rtau * LOG2E);  // fold tau + log2e into q scale
  } else {
    int t = tid - 256;
    float s = 0.f;
#pragma unroll
    for (int ck = 0; ck < 4; ck++) {
      f16x8 v = *(f16x8*)&Ka[t * 40 + ck * 8];
#pragma unroll
      for (int u = 0; u < 8; u++) { float f = (float)v[u]; s = fmaf(f, f, s); }
    }
    rkn[t] = rsqrtf(s);
  }
  __syncthreads();

  // ---- Phase 2: flash-style attention over 64-key chunks, no barriers
  f16* Pme = &Pw[wv * 2304];
  f32x4 acco[2][2] = {};
  float lsum[2][4] = {};
  int loff[4];
#pragma unroll
  for (int r = 0; r < 4; r++) loff[r] = lq * 4 + r - lm + 15;

  for (int n0 = 0; n0 < Tt; n0 += 64) {
    // QK^T: S[2 row-tiles][4 col-tiles]
    f16x8 qf[2], kf[4];
#pragma unroll
    for (int e = 0; e < 2; e++)
      qf[e] = *(f16x8*)&Qa[xidx(wv * 32 + e * 16 + lm, lq * 8, 40)];
#pragma unroll
    for (int nt = 0; nt < 4; nt++)
      kf[nt] = *(f16x8*)&Ka[xidx(n0 + nt * 16 + lm, lq * 8, 40)];
    f32x4 zero = {0.f, 0.f, 0.f, 0.f};
    f32x4 sc[2][4];
#pragma unroll
    for (int e = 0; e < 2; e++)
#pragma unroll
      for (int nt = 0; nt < 4; nt++)
        sc[e][nt] = __builtin_amdgcn_mfma_f32_16x16x32_f16(qf[e], kf[nt], zero,
                                                           0, 0, 0);
    // softmax elementwise in C-layout; dqi tile-uniform, dqj lane-constant
#pragma unroll
    for (int e = 0; e < 2; e++) {
      int rowt = wv * 2 + e;  // row>>4
#pragma unroll
      for (int nt = 0; nt < 4; nt++) {
        int tboff = (rowt - (n0 >> 4) - nt + 15) << 5;
        float rk = rkn[n0 + nt * 16 + lm];
#pragma unroll
        for (int r = 0; r < 4; r++) {
          int row = wv * 32 + e * 16 + lq * 4 + r;
          float p = exp2f(fmaf(sc[e][nt][r], rqn[row] * rk, tb2[tboff + loff[r]]));
          lsum[e][r] += p;
          int rl = e * 16 + lq * 4 + r, cl = nt * 16 + lm;
          Pme[xidx(rl, cl, 72)] = (f16)p;
        }
      }
    }
    asm volatile("s_waitcnt lgkmcnt(0)" ::: "memory");
    // PV: accumulate O[2 row-tiles][2 d-tiles]
#pragma unroll
    for (int ks = 0; ks < 2; ks++) {
      f16x8 pf[2], vf[2];
#pragma unroll
      for (int e = 0; e < 2; e++)
        pf[e] = *(f16x8*)&Pme[xidx(e * 16 + lm, ks * 32 + lq * 8, 72)];
#pragma unroll
      for (int dt = 0; dt < 2; dt++)
        vf[dt] = *(f16x8*)&Vt[vidx(dt * 16 + lm, n0 + ks * 32 + lq * 8)];
#pragma unroll
      for (int e = 0; e < 2; e++)
#pragma unroll
        for (int dt = 0; dt < 2; dt++)
          acco[e][dt] = __builtin_amdgcn_mfma_f32_16x16x32_f16(pf[e], vf[dt],
                                                               acco[e][dt], 0, 0, 0);
    }
  }

  // row-sum reduce across the 16 col-lanes, then normalize + store
#pragma unroll
  for (int e = 0; e < 2; e++)
#pragma unroll
    for (int r = 0; r < 4; r++) {
      float v = lsum[e][r];
      v += __shfl_xor(v, 1);
      v += __shfl_xor(v, 2);
      v += __shfl_xor(v, 4);
      v += __shfl_xor(v, 8);
      lsum[e][r] = __builtin_amdgcn_rcpf(v);
    }
#pragma unroll
  for (int e = 0; e < 2; e++)
#pragma unroll
    for (int dt = 0; dt < 2; dt++)
#pragma unroll
      for (int r = 0; r < 4; r++) {
        int t = wv * 32 + e * 16 + lq * 4 + r;
        int d = dt * 16 + lm;
        attnH[((size_t)b * Tt + t) * Cc + h * HD + d] =
            (f16)(acco[e][dt][r] * lsum[e][r]);
      }
}

// ---------------------------------------------------------------------------
// Kernel 3: proj GEMM (A fp16 row-major [B*T][C]) + transpose to [B][C][T].
// ---------------------------------------------------------------------------
__global__ __launch_bounds__(256) void proj_gemm(
    const f16* __restrict__ A, const float* __restrict__ w,
    const float* __restrict__ bp, float* __restrict__ out) {
  __shared__ __align__(16) float As[16][68];
  __shared__ __align__(16) float Bs[16][68];
  __shared__ __align__(16) float Cs[64][65];
  int tid = threadIdx.x;
  int row0 = blockIdx.x * 64;
  int n0 = blockIdx.y * 64;
  int b = row0 >> 8, t0 = row0 & 255;
  int col_t = tid & 15, row_t = tid >> 4;
  int akc = tid & 15, am0 = tid >> 4;

  float acc[4][4] = {};
  for (int k0 = 0; k0 < Cc; k0 += 16) {
#pragma unroll
    for (int p = 0; p < 4; p++) {
      int m = am0 + p * 16;
      As[akc][m] = (float)A[(size_t)(row0 + m) * Cc + k0 + akc];
    }
#pragma unroll
    for (int p = 0; p < 4; p++)
      Bs[akc][am0 + p * 16] = w[(size_t)(n0 + am0 + p * 16) * Cc + k0 + akc];
    __syncthreads();
#pragma unroll
    for (int kk = 0; kk < 16; kk++) {
      const float4 a4 = *(const float4*)&As[kk][row_t * 4];
      const float4 b4 = *(const float4*)&Bs[kk][col_t * 4];
      const float av[4] = {a4.x, a4.y, a4.z, a4.w};
      const float bv[4] = {b4.x, b4.y, b4.z, b4.w};
#pragma unroll
      for (int i = 0; i < 4; i++)
#pragma unroll
        for (int j = 0; j < 4; j++) acc[i][j] = fmaf(av[i], bv[j], acc[i][j]);
    }
    __syncthreads();
  }

#pragma unroll
  for (int j = 0; j < 4; j++)
#pragma unroll
    for (int i = 0; i < 4; i++)
      Cs[col_t * 4 + j][row_t * 4 + i] = acc[i][j];
  __syncthreads();

  int t63 = tid & 63, ng = tid >> 6;
#pragma unroll
  for (int p = 0; p < 16; p++) {
    int nl = ng + p * 4;
    int n = n0 + nl;
    out[(size_t)b * (Cc * Tt) + (size_t)n * Tt + t0 + t63] =
        Cs[nl][t63] + bp[n];
  }
}

// ---------------------------------------------------------------------------
extern "C" void kernel_launch(void* const* d_in, const int* in_sizes, int n_in,
                              void* d_out, int out_size, void* d_ws,
                              size_t ws_size, hipStream_t stream) {
  const float* x = (const float*)d_in[0];
  const float* w_qkv = (const float*)d_in[1];
  const float* b_qkv = (const float*)d_in[2];
  const float* w_proj = (const float*)d_in[3];
  const float* b_proj = (const float*)d_in[4];
  const float* mw1 = (const float*)d_in[5];
  const float* mb1 = (const float*)d_in[6];
  const float* mw2 = (const float*)d_in[7];
  const float* mb2 = (const float*)d_in[8];
  const float* tau = (const float*)d_in[9];
  float* out = (float*)d_out;

  const size_t NEEDED = (size_t)(TBL * NH + NH) * 4 +
                        (size_t)256 * NH * Tt * HD * 2;
  if (ws_size < NEEDED) return;

  float* table = (float*)d_ws;
  float* tablemax = table + TBL * NH;
  f16* attnH = (f16*)(tablemax + NH);

  table_kernel<<<1, 256, 0, stream>>>(mw1, mb1, mw2, mb2, table, tablemax);
  fused_attn<<<256 * NH, 512, 0, stream>>>(x, w_qkv, b_qkv, table, tablemax,
                                           tau, attnH);
  dim3 g3(1024, 4);
  proj_gemm<<<g3, 256, 0, stream>>>(attnH, w_proj, b_proj, out);
}

// Round 4
// 311.621 us; speedup vs baseline: 3.6366x; 1.4787x over previous
//
#include <hip/hip_runtime.h>
#include <math.h>

#define Cc 256
#define NH 8
#define HD 32
#define Tt 256
#define MH 256
#define TBL 961  // 31*31 distinct relative offsets

typedef _Float16 f16;
typedef f16 f16x8 __attribute__((ext_vector_type(8)));
typedef float f32x4 __attribute__((ext_vector_type(4)));

// XOR-chunk-swizzled LDS helpers (stride in f16 elements, kc = 8-elem chunk).
// key = (row>>2)&3 cancels quad-row bank collisions for frag reads + scatters.
__device__ __forceinline__ f16x8 ld8(const f16* base, int row, int stride,
                                     int kc) {
  return *(const f16x8*)&base[row * stride + ((kc ^ ((row >> 2) & 3)) << 3)];
}
__device__ __forceinline__ void st8(f16* base, int row, int stride, int kc,
                                    f16x8 v) {
  *(f16x8*)&base[row * stride + ((kc ^ ((row >> 2) & 3)) << 3)] = v;
}
__device__ __forceinline__ int sidx(int row, int stride, int col) {
  return row * stride + (((col >> 3) ^ ((row >> 2) & 3)) << 3) + (col & 7);
}

// ---------------------------------------------------------------------------
// Kernel 1: bias MLP on the 961 distinct (di,dj) pairs.
// ---------------------------------------------------------------------------
__global__ __launch_bounds__(256) void table_kernel(
    const float* __restrict__ mw1, const float* __restrict__ mb1,
    const float* __restrict__ mw2, const float* __restrict__ mb2,
    float* __restrict__ table, float* __restrict__ tablemax) {
  __shared__ float s_w1a[MH], s_w1b[MH], s_b1[MH];
  __shared__ float s_w2[NH * MH];
  __shared__ float red[256];
  int tid = threadIdx.x;
  for (int i = tid; i < MH; i += 256) {
    s_w1a[i] = mw1[2 * i];
    s_w1b[i] = mw1[2 * i + 1];
    s_b1[i] = mb1[i];
  }
  for (int i = tid; i < NH * MH; i += 256) s_w2[i] = mw2[i];
  __syncthreads();

  float lmax[NH];
#pragma unroll
  for (int j = 0; j < NH; j++) lmax[j] = -1e30f;

  for (int idx = tid; idx < TBL; idx += 256) {
    float fdi = (float)(idx / 31 - 15);
    float fdj = (float)(idx % 31 - 15);
    float d0 = (fdi > 0.f ? 1.f : (fdi < 0.f ? -1.f : 0.f)) * log1pf(fabsf(fdi));
    float d1 = (fdj > 0.f ? 1.f : (fdj < 0.f ? -1.f : 0.f)) * log1pf(fabsf(fdj));
    float o[NH];
#pragma unroll
    for (int j = 0; j < NH; j++) o[j] = mb2[j];
    for (int m = 0; m < MH; m++) {
      float hid = fmaxf(fmaf(d0, s_w1a[m], fmaf(d1, s_w1b[m], s_b1[m])), 0.f);
#pragma unroll
      for (int j = 0; j < NH; j++) o[j] = fmaf(hid, s_w2[j * MH + m], o[j]);
    }
#pragma unroll
    for (int j = 0; j < NH; j++) {
      table[j * TBL + idx] = o[j];
      lmax[j] = fmaxf(lmax[j], o[j]);
    }
  }

  for (int j = 0; j < NH; j++) {
    __syncthreads();
    red[tid] = lmax[j];
    __syncthreads();
    for (int s = 128; s > 0; s >>= 1) {
      if (tid < s) red[tid] = fmaxf(red[tid], red[tid + s]);
      __syncthreads();
    }
    if (tid == 0) tablemax[j] = red[0];
  }
}

// ---------------------------------------------------------------------------
// Kernel 2: fully-MFMA fused QKV + cosine-sim attention.  Block = (b,h),
// 512 threads = 8 waves.  LDS 74112 B -> 2 blocks/CU (4 waves/SIMD).
// Q,K pre-normalized in LDS (rtau*log2e folded into Q) -> softmax element is
// just exp2(sc + tb2).  32-key chunks, no barriers in phase 2.
// ---------------------------------------------------------------------------
__global__ __launch_bounds__(512, 4) void fused_attn(
    const float* __restrict__ x, const float* __restrict__ w_qkv,
    const float* __restrict__ b_qkv, const float* __restrict__ table,
    const float* __restrict__ tablemax, const float* __restrict__ tau,
    f16* __restrict__ attnH) {
  __shared__ __align__(16) char smem[74112];
  f16* Qa = (f16*)(smem);            // [t=256][d=32] stride 32, 16384 B
  f16* Ka = (f16*)(smem + 16384);    // 16384 B
  f16* Vt = (f16*)(smem + 32768);    // [d=32][t=256] stride 264, 16896 B
  f16* Pw = (f16*)(smem + 49664);    // 8 waves x 32x40, 20480 B
  float* tb2 = (float*)(smem + 70144);  // 31*32 fp32, 3968 B (init after ph1)
  f16* Xa = (f16*)(smem + 49664);    // phase-1 alias: [t=256][c=32], 16384 B
  f16* Wa = (f16*)(smem + 66048);    // phase-1 alias: [n=96][c=32], 6144 B

  int tid = threadIdx.x;
  int bh = blockIdx.x, b = bh >> 3, h = bh & 7;
  int wv = tid >> 6, ln = tid & 63, lq = ln >> 4, lm = ln & 15;

  const float LOG2E = 1.4426950408889634f;
  float rtau = 1.0f / fmaxf(tau[h], 0.01f);
  float tmaxh = tablemax[h];

  // per-lane qkv bias for the 6 n-tiles (n = nt*16 + lm)
  float bj[6];
#pragma unroll
  for (int nt = 0; nt < 6; nt++) {
    int n = nt * 16 + lm;
    int row = ((n >> 5) << 8) + (h << 5) + (n & 31);
    bj[nt] = b_qkv[row];
  }

  // ---- Phase 1: QKV GEMM, M=256 N=96 K=256, MFMA 16x16x32_f16
  f32x4 acc[2][6] = {};
  for (int c0 = 0; c0 < Cc; c0 += 32) {
    {  // stage Xa[t][c'] fp16 (transpose of x[b][c][t]); coalesced reads
      int t = tid & 255, cg = tid >> 8;
      f16x8 v0, v1;
#pragma unroll
      for (int cc = 0; cc < 8; cc++)
        v0[cc] = (f16)x[(size_t)b * 65536 + (size_t)(c0 + cg * 16 + cc) * 256 + t];
#pragma unroll
      for (int cc = 0; cc < 8; cc++)
        v1[cc] = (f16)x[(size_t)b * 65536 + (size_t)(c0 + cg * 16 + 8 + cc) * 256 + t];
      st8(Xa, t, 32, cg * 2 + 0, v0);
      st8(Xa, t, 32, cg * 2 + 1, v1);
    }
    if (tid < 384) {  // stage Wa[n][c'] fp16
      int n = tid >> 2, ck = tid & 3;
      int row = ((n >> 5) << 8) + (h << 5) + (n & 31);
      const float* wp = w_qkv + (size_t)row * Cc + c0 + ck * 8;
      f16x8 v;
#pragma unroll
      for (int u = 0; u < 8; u++) v[u] = (f16)wp[u];
      st8(Wa, n, 32, ck, v);
    }
    __syncthreads();
    f16x8 af[2], bf[6];
#pragma unroll
    for (int e = 0; e < 2; e++) af[e] = ld8(Xa, wv * 32 + e * 16 + lm, 32, lq);
#pragma unroll
    for (int nt = 0; nt < 6; nt++) bf[nt] = ld8(Wa, nt * 16 + lm, 32, lq);
#pragma unroll
    for (int e = 0; e < 2; e++)
#pragma unroll
      for (int nt = 0; nt < 6; nt++)
        acc[e][nt] = __builtin_amdgcn_mfma_f32_16x16x32_f16(af[e], bf[nt],
                                                            acc[e][nt], 0, 0, 0);
    __syncthreads();
  }

  // epilogue: + bias, scatter to Qa/Ka (t-major) and Vt (d-major)
#pragma unroll
  for (int e = 0; e < 2; e++) {
#pragma unroll
    for (int nt = 0; nt < 6; nt++) {
      int d = (nt & 1) * 16 + lm;
#pragma unroll
      for (int r = 0; r < 4; r++) {
        int t = wv * 32 + e * 16 + lq * 4 + r;
        f16 v = (f16)(acc[e][nt][r] + bj[nt]);
        if (nt < 2)      Qa[sidx(t, 32, d)] = v;
        else if (nt < 4) Ka[sidx(t, 32, d)] = v;
        else             Vt[sidx(d, 264, t)] = v;
      }
    }
  }
  __syncthreads();

  // normalize Q,K rows in place; init tb2 (aliased Wa region is dead now)
  if (tid < 256) {
    int t = tid;
    float s = 0.f;
    f16x8 v[4];
#pragma unroll
    for (int ck = 0; ck < 4; ck++) {
      v[ck] = *(f16x8*)&Qa[t * 32 + ck * 8];
#pragma unroll
      for (int u = 0; u < 8; u++) { float f = (float)v[ck][u]; s = fmaf(f, f, s); }
    }
    float sc_ = rsqrtf(s) * rtau * LOG2E;
#pragma unroll
    for (int ck = 0; ck < 4; ck++) {
      f16x8 o;
#pragma unroll
      for (int u = 0; u < 8; u++) o[u] = (f16)((float)v[ck][u] * sc_);
      *(f16x8*)&Qa[t * 32 + ck * 8] = o;
    }
  } else {
    int t = tid - 256;
    float s = 0.f;
    f16x8 v[4];
#pragma unroll
    for (int ck = 0; ck < 4; ck++) {
      v[ck] = *(f16x8*)&Ka[t * 32 + ck * 8];
#pragma unroll
      for (int u = 0; u < 8; u++) { float f = (float)v[ck][u]; s = fmaf(f, f, s); }
    }
    float sc_ = rsqrtf(s);
#pragma unroll
    for (int ck = 0; ck < 4; ck++) {
      f16x8 o;
#pragma unroll
      for (int u = 0; u < 8; u++) o[u] = (f16)((float)v[ck][u] * sc_);
      *(f16x8*)&Ka[t * 32 + ck * 8] = o;
    }
  }
  for (int i = tid; i < TBL; i += 512) {
    int di_ = i / 31, dj_ = i % 31;
    tb2[di_ * 32 + dj_] = (table[h * TBL + i] - tmaxh - rtau * 1.0001f) * LOG2E;
  }
  __syncthreads();

  // ---- Phase 2: flash attention over 32-key chunks, no barriers
  f16* Pme = Pw + wv * 1280;  // 32 x 40
  f16x8 qf[2];
#pragma unroll
  for (int e = 0; e < 2; e++) qf[e] = ld8(Qa, wv * 32 + e * 16 + lm, 32, lq);

  f32x4 acco[2][2] = {};
  float lsum[2][4] = {};
  int loff[4];
#pragma unroll
  for (int r = 0; r < 4; r++) loff[r] = lq * 4 + r - lm + 15;
  int rowt = wv * 2;

  for (int n0 = 0; n0 < Tt; n0 += 32) {
    f16x8 kf[2];
#pragma unroll
    for (int nt = 0; nt < 2; nt++)
      kf[nt] = ld8(Ka, n0 + nt * 16 + lm, 32, lq);
    f32x4 zero = {0.f, 0.f, 0.f, 0.f};
    f32x4 sc[2][2];
#pragma unroll
    for (int e = 0; e < 2; e++)
#pragma unroll
      for (int nt = 0; nt < 2; nt++)
        sc[e][nt] = __builtin_amdgcn_mfma_f32_16x16x32_f16(qf[e], kf[nt], zero,
                                                           0, 0, 0);
#pragma unroll
    for (int e = 0; e < 2; e++) {
#pragma unroll
      for (int nt = 0; nt < 2; nt++) {
        int tboff = (rowt + e - (n0 >> 4) - nt + 15) << 5;
#pragma unroll
        for (int r = 0; r < 4; r++) {
          float p = exp2f(sc[e][nt][r] + tb2[tboff + loff[r]]);
          lsum[e][r] += p;
          Pme[(e * 16 + lq * 4 + r) * 40 + nt * 16 + lm] = (f16)p;
        }
      }
    }
    asm volatile("s_waitcnt lgkmcnt(0)" ::: "memory");
    f16x8 pf[2], vf[2];
#pragma unroll
    for (int e = 0; e < 2; e++)
      pf[e] = *(f16x8*)&Pme[(e * 16 + lm) * 40 + lq * 8];
#pragma unroll
    for (int dt = 0; dt < 2; dt++)
      vf[dt] = ld8(Vt, dt * 16 + lm, 264, (n0 >> 3) + lq);
#pragma unroll
    for (int e = 0; e < 2; e++)
#pragma unroll
      for (int dt = 0; dt < 2; dt++)
        acco[e][dt] = __builtin_amdgcn_mfma_f32_16x16x32_f16(pf[e], vf[dt],
                                                             acco[e][dt], 0, 0, 0);
  }

  // row-sum reduce across the 16 col-lanes, then normalize + store
#pragma unroll
  for (int e = 0; e < 2; e++)
#pragma unroll
    for (int r = 0; r < 4; r++) {
      float v = lsum[e][r];
      v += __shfl_xor(v, 1);
      v += __shfl_xor(v, 2);
      v += __shfl_xor(v, 4);
      v += __shfl_xor(v, 8);
      lsum[e][r] = __builtin_amdgcn_rcpf(v);
    }
#pragma unroll
  for (int e = 0; e < 2; e++)
#pragma unroll
    for (int dt = 0; dt < 2; dt++)
#pragma unroll
      for (int r = 0; r < 4; r++) {
        int t = wv * 32 + e * 16 + lq * 4 + r;
        int d = dt * 16 + lm;
        attnH[((size_t)b * Tt + t) * Cc + h * HD + d] =
            (f16)(acco[e][dt][r] * lsum[e][r]);
      }
}

// ---------------------------------------------------------------------------
// Kernel 3: MFMA proj GEMM.  A fp16 [B*T][256] x W[256][256] -> out[b][c][t].
// Computed as mfma(W-frag(c), A-frag(t)) so C col = t -> coalesced stores.
// Block 256 thr (4 waves), tile 128(c-? no: rows=bt)..: 128 bt x 128 c.
// ---------------------------------------------------------------------------
__global__ __launch_bounds__(256, 4) void proj_gemm(
    const f16* __restrict__ A, const float* __restrict__ w,
    const float* __restrict__ bp, float* __restrict__ out) {
  __shared__ __align__(16) f16 Xs[128 * 32];  // rows t, stride 32
  __shared__ __align__(16) f16 Ws[128 * 32];  // rows c, stride 32
  __shared__ float sB[128];
  int tid = threadIdx.x;
  int row0 = blockIdx.x * 128;  // global bt row
  int n0g = blockIdx.y * 128;   // global c col
  int b = row0 >> 8, t0 = row0 & 255;
  int wv = tid >> 6, ln = tid & 63, lq = ln >> 4, lm = ln & 15;
  int cw = (wv & 1) * 64, tw = (wv >> 1) * 64;

  if (tid < 128) sB[tid] = bp[n0g + tid];

  f32x4 acc[4][4] = {};
  for (int k0 = 0; k0 < Cc; k0 += 32) {
#pragma unroll
    for (int it = 0; it < 2; it++) {
      int idx = it * 256 + tid;
      int t = idx >> 2, ck = idx & 3;
      f16x8 v = *(const f16x8*)&A[(size_t)(row0 + t) * Cc + k0 + ck * 8];
      st8(Xs, t, 32, ck, v);
    }
#pragma unroll
    for (int it = 0; it < 2; it++) {
      int idx = it * 256 + tid;
      int n = idx >> 2, ck = idx & 3;
      const float* wp = w + (size_t)(n0g + n) * Cc + k0 + ck * 8;
      float4 w0 = *(const float4*)wp;
      float4 w1 = *(const float4*)(wp + 4);
      f16x8 v;
      v[0] = (f16)w0.x; v[1] = (f16)w0.y; v[2] = (f16)w0.z; v[3] = (f16)w0.w;
      v[4] = (f16)w1.x; v[5] = (f16)w1.y; v[6] = (f16)w1.z; v[7] = (f16)w1.w;
      st8(Ws, n, 32, ck, v);
    }
    __syncthreads();
    f16x8 wf[4], af[4];
#pragma unroll
    for (int i = 0; i < 4; i++) wf[i] = ld8(Ws, cw + i * 16 + lm, 32, lq);
#pragma unroll
    for (int j = 0; j < 4; j++) af[j] = ld8(Xs, tw + j * 16 + lm, 32, lq);
#pragma unroll
    for (int i = 0; i < 4; i++)
#pragma unroll
      for (int j = 0; j < 4; j++)
        acc[i][j] = __builtin_amdgcn_mfma_f32_16x16x32_f16(wf[i], af[j],
                                                           acc[i][j], 0, 0, 0);
    __syncthreads();
  }

  // epilogue: C row = c-local, col = t-local; stores contiguous in t
#pragma unroll
  for (int i = 0; i < 4; i++)
#pragma unroll
    for (int r = 0; r < 4; r++) {
      int crl = cw + i * 16 + lq * 4 + r;
      float bias = sB[crl];
#pragma unroll
      for (int j = 0; j < 4; j++) {
        int tcl = tw + j * 16 + lm;
        out[(size_t)b * 65536 + (size_t)(n0g + crl) * 256 + t0 + tcl] =
            acc[i][j][r] + bias;
      }
    }
}

// ---------------------------------------------------------------------------
extern "C" void kernel_launch(void* const* d_in, const int* in_sizes, int n_in,
                              void* d_out, int out_size, void* d_ws,
                              size_t ws_size, hipStream_t stream) {
  const float* x = (const float*)d_in[0];
  const float* w_qkv = (const float*)d_in[1];
  const float* b_qkv = (const float*)d_in[2];
  const float* w_proj = (const float*)d_in[3];
  const float* b_proj = (const float*)d_in[4];
  const float* mw1 = (const float*)d_in[5];
  const float* mb1 = (const float*)d_in[6];
  const float* mw2 = (const float*)d_in[7];
  const float* mb2 = (const float*)d_in[8];
  const float* tau = (const float*)d_in[9];
  float* out = (float*)d_out;

  const size_t NEEDED = (size_t)(TBL * NH + NH) * 4 +
                        (size_t)256 * NH * Tt * HD * 2;
  if (ws_size < NEEDED) return;

  float* table = (float*)d_ws;
  float* tablemax = table + TBL * NH;
  f16* attnH = (f16*)(tablemax + NH);

  table_kernel<<<1, 256, 0, stream>>>(mw1, mb1, mw2, mb2, table, tablemax);
  fused_attn<<<256 * NH, 512, 0, stream>>>(x, w_qkv, b_qkv, table, tablemax,
                                           tau, attnH);
  dim3 g3(512, 2);
  proj_gemm<<<g3, 256, 0, stream>>>(attnH, w_proj, b_proj, out);
}